// Round 4
// baseline (269.670 us; speedup 1.0000x reference)
//
#include <hip/hip_runtime.h>
#include <hip/hip_cooperative_groups.h>
#include <math.h>

namespace cg = cooperative_groups;

#define NATOMS 4096
#define FDIM   256
#define NHEAD  8
#define DHEAD  32
#define NGRP   128
#define NBLK   256

typedef __bf16 bf16x8 __attribute__((ext_vector_type(8)));
typedef float  floatx4 __attribute__((ext_vector_type(4)));
typedef unsigned short u16x4 __attribute__((ext_vector_type(4)));

__device__ __forceinline__ float silu_f(float x) {
    return x / (1.0f + __expf(-x));
}

__device__ __forceinline__ unsigned short f2bf(float f) {
    union { float f; unsigned int u; } a;
    a.f = f;
    unsigned int r = a.u + 0x7FFF + ((a.u >> 16) & 1);   // RNE
    return (unsigned short)(r >> 16);
}

// Shared memory reused across phases.
struct SharedMem {
    union {
        struct {                     // attention phase (~14.5 KB)
            float4 qt4[64 * 8];
            float4 vt4[32 * 8];
            float  wred[8][32];
            float  w[32];
            float  red[8][32];
        } a;
        struct {                     // small-gemm phase (~9.2 KB)
            float As[32][36];
            float Bs[32][36];
        } g;
    };
};

// ---------------------------------------------------------------------------
// 32x32-tile NT gemm body on blocks 0..31: C[128,256] = A @ B^T (+rowScale*b)
// ---------------------------------------------------------------------------
__device__ void gemm32_body(SharedMem& sm,
                            const float* __restrict__ A, const float* __restrict__ B,
                            const float* __restrict__ bias, const float* __restrict__ rowScale,
                            float* __restrict__ C, int act, int blk)
{
    const int K = FDIM, Ncols = FDIM;
    int tid = threadIdx.x;
    int bm = (blk >> 3) * 32;     // 4 row-tiles
    int bn = (blk & 7) * 32;      // 8 col-tiles
    int tx = tid & 15;
    int ty = tid >> 4;
    int lm = tid >> 3;
    int lk = (tid & 7) << 2;

    float acc[2][2] = {};

    for (int kt = 0; kt < K; kt += 32) {
        const float4 av = *(const float4*)(A + (size_t)(bm + lm) * K + kt + lk);
        const float4 bv = *(const float4*)(B + (size_t)(bn + lm) * K + kt + lk);
        sm.g.As[lk + 0][lm] = av.x; sm.g.As[lk + 1][lm] = av.y;
        sm.g.As[lk + 2][lm] = av.z; sm.g.As[lk + 3][lm] = av.w;
        sm.g.Bs[lk + 0][lm] = bv.x; sm.g.Bs[lk + 1][lm] = bv.y;
        sm.g.Bs[lk + 2][lm] = bv.z; sm.g.Bs[lk + 3][lm] = bv.w;
        __syncthreads();

#pragma unroll
        for (int kk = 0; kk < 32; ++kk) {
            float a0 = sm.g.As[kk][ty * 2], a1 = sm.g.As[kk][ty * 2 + 1];
            float c0 = sm.g.Bs[kk][tx * 2], c1 = sm.g.Bs[kk][tx * 2 + 1];
            acc[0][0] = fmaf(a0, c0, acc[0][0]);
            acc[0][1] = fmaf(a0, c1, acc[0][1]);
            acc[1][0] = fmaf(a1, c0, acc[1][0]);
            acc[1][1] = fmaf(a1, c1, acc[1][1]);
        }
        __syncthreads();
    }

#pragma unroll
    for (int i = 0; i < 2; ++i) {
        int m = bm + ty * 2 + i;
        float rs = rowScale ? rowScale[m] : 1.0f;
#pragma unroll
        for (int j = 0; j < 2; ++j) {
            int n = bn + tx * 2 + j;
            float vv = acc[i][j] + rs * bias[n];
            if (act) vv = silu_f(vv);
            C[(size_t)m * Ncols + n] = vv;
        }
    }
}

// ---------------------------------------------------------------------------
// The whole pipeline in one cooperative kernel. 256 blocks x 256 threads.
// ---------------------------------------------------------------------------
__global__ __launch_bounds__(256) void mega_kernel(
    const float* __restrict__ x, const int* __restrict__ seg,
    const float* __restrict__ Wq, const float* __restrict__ Wk, const float* __restrict__ Wv,
    const float* __restrict__ bq, const float* __restrict__ bk, const float* __restrict__ bv,
    const float* __restrict__ Wo1, const float* __restrict__ bo1,
    const float* __restrict__ Wo2, const float* __restrict__ bo2,
    float* __restrict__ out,
    unsigned short* __restrict__ xb, unsigned short* __restrict__ Wb,
    float* __restrict__ qkv, float* __restrict__ Ysum, float* __restrict__ S,
    float* __restrict__ cntf, int* __restrict__ off)
{
    cg::grid_group grid = cg::this_grid();
    __shared__ SharedMem sm;

    const int tid = threadIdx.x;
    const int bid = blockIdx.x;

    // ================= P0: bf16 conversion + group offsets ==================
    if (bid == 0 && tid < NGRP) {
        int g = tid;
        auto lb = [&](int val) {
            int lo = 0, hi = NATOMS;
            while (lo < hi) {
                int mid = (lo + hi) >> 1;
                if (seg[mid] < val) lo = mid + 1; else hi = mid;
            }
            return lo;
        };
        int a = lb(g);
        int b = lb(g + 1);
        off[g] = a;
        if (g == NGRP - 1) off[NGRP] = NATOMS;
        cntf[g] = (float)(b - a);
    }

    const unsigned int NX4 = 262144;                 // x float4 units
    const unsigned int NW4 = 16384;                  // per-W float4 units
    const unsigned int NTOT = NX4 + 3 * NW4;         // 311296
    for (unsigned int u = bid * 256u + tid; u < NTOT; u += NBLK * 256u) {
        float4 fv;
        u16x4* dst;
        if (u < NX4) {
            fv = ((const float4*)x)[u];
            dst = (u16x4*)xb + u;
        } else {
            unsigned int r = u - NX4;
            unsigned int w = r / NW4;
            unsigned int i = r - w * NW4;
            const float* W = (w == 0) ? Wq : (w == 1) ? Wk : Wv;
            fv = ((const float4*)W)[i];
            dst = (u16x4*)Wb + (size_t)w * NW4 + i;
        }
        u16x4 o;
        o[0] = f2bf(fv.x); o[1] = f2bf(fv.y); o[2] = f2bf(fv.z); o[3] = f2bf(fv.w);
        *dst = o;
    }
    grid.sync();

    // ================= P1: QKV projection via bf16 MFMA =====================
    // D[4096,768] = xb @ Wb^T + bias, scattered into fp32 q|k|v.
    // 384 tile-jobs of 64(m) x 128(n); 4 waves per block in 2x2.
    {
        int lane = tid & 63;
        int ww = tid >> 6;
        int wrow = ww >> 1, wcol = ww & 1;
        int l15 = lane & 15;
        int quad = lane >> 4;
        int kq = quad * 8;

        for (int job = bid; job < 384; job += NBLK) {
            int tm = job & 63;       // 0..63
            int tn = job >> 6;       // 0..5
            int m_base = tm * 64 + wrow * 32;
            int n_base = tn * 128 + wcol * 64;

            floatx4 acc[2][4] = {};

            const unsigned short* arow0 = xb + (size_t)(m_base + l15) * 256 + kq;
            const unsigned short* arow1 = arow0 + 16 * 256;
            const unsigned short* brow[4];
#pragma unroll
            for (int ni = 0; ni < 4; ++ni)
                brow[ni] = Wb + (size_t)(n_base + ni * 16 + l15) * 256 + kq;

#pragma unroll
            for (int ks = 0; ks < 8; ++ks) {
                int ko = ks * 32;
                bf16x8 a0 = *(const bf16x8*)(arow0 + ko);
                bf16x8 a1 = *(const bf16x8*)(arow1 + ko);
#pragma unroll
                for (int ni = 0; ni < 4; ++ni) {
                    bf16x8 b = *(const bf16x8*)(brow[ni] + ko);
                    acc[0][ni] = __builtin_amdgcn_mfma_f32_16x16x32_bf16(a0, b, acc[0][ni], 0, 0, 0);
                    acc[1][ni] = __builtin_amdgcn_mfma_f32_16x16x32_bf16(a1, b, acc[1][ni], 0, 0, 0);
                }
            }

#pragma unroll
            for (int mi = 0; mi < 2; ++mi) {
#pragma unroll
                for (int ni = 0; ni < 4; ++ni) {
                    int col_g = n_base + ni * 16 + l15;
                    int w = col_g >> 8, c = col_g & 255;
                    const float* bptr = (w == 0) ? bq : (w == 1) ? bk : bv;
                    float bias = bptr[c];
                    float* outp = qkv + (size_t)w * ((size_t)NATOMS * FDIM) + c;
#pragma unroll
                    for (int r = 0; r < 4; ++r) {
                        int row = m_base + mi * 16 + quad * 4 + r;
                        outp[(size_t)row * FDIM] = acc[mi][ni][r] + bias;
                    }
                }
            }
        }
    }
    grid.sync();

    // ================= P2: block-diagonal attention =========================
    // Ysum[g, h*32+d] = sum_j (sum_i silu(q_i.k_j)) * v_j[d]; 4 jobs/block.
    {
        const float* q = qkv;
        const float* k = qkv + (size_t)NATOMS * FDIM;
        const float* v = qkv + 2 * (size_t)NATOMS * FDIM;

        int jj = tid & 31;
        int iq = tid >> 5;
        int d = tid & 31;
        int r = tid >> 5;

        for (int t = 0; t < 4; ++t) {
            int job = bid * 4 + t;          // 0..1023
            int g = job >> 3, h = job & 7;

            int base = off[g];
            int end  = off[g + 1];
            base = min(max(base, 0), NATOMS);   // poison-safe clamps
            end  = min(max(end, base), NATOMS);
            int n = end - base;

            const float4* q4 = (const float4*)(q + (size_t)base * FDIM) + h * 8;
            const float4* k4 = (const float4*)(k + (size_t)base * FDIM) + h * 8;
            const float4* v4 = (const float4*)(v + (size_t)base * FDIM) + h * 8;

            float accY = 0.0f;

            for (int j0 = 0; j0 < n; j0 += 32) {
                int jt_n = min(32, n - j0);
                __syncthreads();
                for (int idx = tid; idx < jt_n * 8; idx += 256)
                    sm.a.vt4[idx] = v4[(size_t)(j0 + (idx >> 3)) * 64 + (idx & 7)];

                float4 kr[8];
                {
                    int jrow = (jj < jt_n) ? (j0 + jj) : j0;
#pragma unroll
                    for (int c = 0; c < 8; ++c) kr[c] = k4[(size_t)jrow * 64 + c];
                }

                float wpart = 0.0f;
                for (int i0 = 0; i0 < n; i0 += 64) {
                    int it_n = min(64, n - i0);
                    __syncthreads();
                    for (int idx = tid; idx < it_n * 8; idx += 256)
                        sm.a.qt4[idx] = q4[(size_t)(i0 + (idx >> 3)) * 64 + (idx & 7)];
                    __syncthreads();
                    if (jj < jt_n) {
                        for (int ii = iq; ii < it_n; ii += 8) {
                            const float4* qr = &sm.a.qt4[ii * 8];
                            float s = 0.0f;
#pragma unroll
                            for (int c = 0; c < 8; ++c) {
                                float4 a = qr[c];
                                s = fmaf(a.x, kr[c].x, s);
                                s = fmaf(a.y, kr[c].y, s);
                                s = fmaf(a.z, kr[c].z, s);
                                s = fmaf(a.w, kr[c].w, s);
                            }
                            wpart += silu_f(s);
                        }
                    }
                }
                sm.a.wred[iq][jj] = wpart;
                __syncthreads();
                if (tid < 32) {
                    float s = 0.0f;
#pragma unroll
                    for (int rr = 0; rr < 8; ++rr) s += sm.a.wred[rr][tid];
                    sm.a.w[tid] = s;
                }
                __syncthreads();
                const float* vts = (const float*)sm.a.vt4;
                for (int j = r; j < jt_n; j += 8)
                    accY = fmaf(sm.a.w[j], vts[j * 32 + d], accY);
            }

            sm.a.red[r][d] = accY;
            __syncthreads();
            if (r == 0) {
                float s = 0.0f;
#pragma unroll
                for (int rr = 0; rr < 8; ++rr) s += sm.a.red[rr][d];
                Ysum[(size_t)g * FDIM + h * DHEAD + d] = s;
            }
            __syncthreads();   // red/LDS safe for next job
        }
    }
    grid.sync();

    // ================= P3: S = Ysum @ Wo1^T + cnt*bo1 =======================
    if (bid < 32) gemm32_body(sm, Ysum, Wo1, bo1, cntf, S, 0, bid);
    grid.sync();

    // ================= P4: out = silu(S @ Wo2^T + bo2) ======================
    if (bid < 32) gemm32_body(sm, S, Wo2, bo2, nullptr, out, 1, bid);
}

// ---------------------------------------------------------------------------
extern "C" void kernel_launch(void* const* d_in, const int* in_sizes, int n_in,
                              void* d_out, int out_size, void* d_ws, size_t ws_size,
                              hipStream_t stream) {
    const float* x    = (const float*)d_in[0];
    const int*   eidx = (const int*)  d_in[1];
    const float* Wq   = (const float*)d_in[2];
    const float* bq   = (const float*)d_in[3];
    const float* Wk   = (const float*)d_in[4];
    const float* bk   = (const float*)d_in[5];
    const float* Wv   = (const float*)d_in[6];
    const float* bv   = (const float*)d_in[7];
    const float* Wo1  = (const float*)d_in[8];
    const float* bo1  = (const float*)d_in[9];
    const float* Wo2  = (const float*)d_in[10];
    const float* bo2  = (const float*)d_in[11];
    float* out = (float*)d_out;

    const int* seg = eidx + NATOMS;

    const size_t NF = (size_t)NATOMS * FDIM;   // 1,048,576
    const size_t GF = (size_t)NGRP * FDIM;     // 32,768

    float* qkv   = (float*)d_ws;               // q|k|v contiguous, 3*NF
    float* Ysum  = qkv + 3 * NF;
    float* S     = Ysum + GF;
    float* cntf  = S + GF;                     // 128
    int*   off   = (int*)(cntf + NGRP);        // 129 ints, pad to 160
    unsigned short* xb = (unsigned short*)((float*)off + 160);  // NF bf16
    unsigned short* Wb = xb + NF;              // 768*256 bf16

    void* args[] = {
        (void*)&x, (void*)&seg,
        (void*)&Wq, (void*)&Wk, (void*)&Wv,
        (void*)&bq, (void*)&bk, (void*)&bv,
        (void*)&Wo1, (void*)&bo1, (void*)&Wo2, (void*)&bo2,
        (void*)&out,
        (void*)&xb, (void*)&Wb,
        (void*)&qkv, (void*)&Ysum, (void*)&S,
        (void*)&cntf, (void*)&off
    };
    hipLaunchCooperativeKernel((const void*)mega_kernel,
                               dim3(NBLK), dim3(256), args, 0, stream);
}

// Round 5
// 153.212 us; speedup vs baseline: 1.7601x; 1.7601x over previous
//
#include <hip/hip_runtime.h>
#include <math.h>

#define NATOMS 4096
#define FDIM   256
#define NHEAD  8
#define DHEAD  32
#define NGRP   128

typedef __bf16 bf16x8 __attribute__((ext_vector_type(8)));
typedef float  floatx4 __attribute__((ext_vector_type(4)));

__device__ __forceinline__ float silu_f(float x) {
    return x / (1.0f + __expf(-x));
}

// load 8 consecutive fp32 and convert to a bf16x8 MFMA fragment (RNE)
__device__ __forceinline__ bf16x8 cvt8(const float* __restrict__ p) {
    float4 f0 = *(const float4*)p;
    float4 f1 = *(const float4*)(p + 4);
    bf16x8 r;
    r[0] = (__bf16)f0.x; r[1] = (__bf16)f0.y; r[2] = (__bf16)f0.z; r[3] = (__bf16)f0.w;
    r[4] = (__bf16)f1.x; r[5] = (__bf16)f1.y; r[6] = (__bf16)f1.z; r[7] = (__bf16)f1.w;
    return r;
}

// ---------------------------------------------------------------------------
// K1: 577 blocks.
//  bid <  512 : QKV projection tile via bf16 MFMA, fp32 inputs cvt'd inline.
//               D[4096,768] = x @ [Wq|Wk|Wv]^T + bias -> fp32 q|k|v.
//               512 jobs = 64 m-tiles(64) x 8 n-tiles(96); 4 waves 2x2,
//               wave tile 32m x 48n (2 m-frags x 3 n-frags of 16x16x32).
//  512..575   : A2 = Wo2 @ Wo1  (fp32 NN gemm, 32x32 tiles) — exact algebra:
//               out = silu(Ysum@A2^T + cnt*c1 + bo2), c1 = Wo2@bo1.
//  bid == 576 : group offsets + counts; c1 = Wo2 @ bo1 (wave-reduced).
// ---------------------------------------------------------------------------
__global__ __launch_bounds__(256) void k1_qkv_a2(
    const float* __restrict__ x, const int* __restrict__ seg,
    const float* __restrict__ Wq, const float* __restrict__ Wk, const float* __restrict__ Wv,
    const float* __restrict__ bq, const float* __restrict__ bk, const float* __restrict__ bv,
    const float* __restrict__ Wo1, const float* __restrict__ bo1,
    const float* __restrict__ Wo2,
    float* __restrict__ qkv, float* __restrict__ A2, float* __restrict__ c1,
    float* __restrict__ cntf, int* __restrict__ off)
{
    __shared__ float As[32][33];
    __shared__ float Bs[32][33];

    const int tid = threadIdx.x;
    const int bid = blockIdx.x;

    if (bid < 512) {
        // ---------------- QKV MFMA tile ----------------
        int lane = tid & 63;
        int ww = tid >> 6;
        int wrow = ww >> 1, wcol = ww & 1;
        int tm = bid & 63;
        int tn = bid >> 6;                 // 0..7
        int m_base = tm * 64 + wrow * 32;
        int n_base = tn * 96 + wcol * 48;

        int l15 = lane & 15;
        int quad = lane >> 4;
        int kq = quad * 8;

        floatx4 acc[2][3] = {};

        const float* arow0 = x + (size_t)(m_base + l15) * 256 + kq;
        const float* arow1 = arow0 + 16 * 256;
        const float* brow[3];
        const float* bias[3];
#pragma unroll
        for (int ni = 0; ni < 3; ++ni) {
            int col = n_base + ni * 16 + l15;
            int w = col >> 8, c = col & 255;
            const float* W = (w == 0) ? Wq : (w == 1) ? Wk : Wv;
            brow[ni] = W + (size_t)c * 256 + kq;
            bias[ni] = ((w == 0) ? bq : (w == 1) ? bk : bv) + c;
        }

#pragma unroll
        for (int ks = 0; ks < 8; ++ks) {
            int ko = ks * 32;
            bf16x8 a0 = cvt8(arow0 + ko);
            bf16x8 a1 = cvt8(arow1 + ko);
#pragma unroll
            for (int ni = 0; ni < 3; ++ni) {
                bf16x8 b = cvt8(brow[ni] + ko);
                acc[0][ni] = __builtin_amdgcn_mfma_f32_16x16x32_bf16(a0, b, acc[0][ni], 0, 0, 0);
                acc[1][ni] = __builtin_amdgcn_mfma_f32_16x16x32_bf16(a1, b, acc[1][ni], 0, 0, 0);
            }
        }

#pragma unroll
        for (int mi = 0; mi < 2; ++mi) {
#pragma unroll
            for (int ni = 0; ni < 3; ++ni) {
                int col = n_base + ni * 16 + l15;
                int w = col >> 8, c = col & 255;
                float bb = *bias[ni];
                float* outp = qkv + (size_t)w * ((size_t)NATOMS * FDIM) + c;
#pragma unroll
                for (int r = 0; r < 4; ++r) {
                    int row = m_base + mi * 16 + quad * 4 + r;
                    outp[(size_t)row * FDIM] = acc[mi][ni][r] + bb;
                }
            }
        }
    } else if (bid < 576) {
        // ---------------- A2 = Wo2 @ Wo1 (fp32 NN, 32x32 tile) ----------------
        int t = bid - 512;
        int i0 = (t >> 3) * 32;
        int j0 = (t & 7) * 32;
        int tx = tid & 15;
        int ty = tid >> 4;
        int lm = tid >> 3;              // 0..31
        int lk = (tid & 7) << 2;        // 0..28

        float acc[2][2] = {};

        for (int kt = 0; kt < 256; kt += 32) {
            const float4 av = *(const float4*)(Wo2 + (size_t)(i0 + lm) * 256 + kt + lk);
            const float4 bv = *(const float4*)(Wo1 + (size_t)(kt + lm) * 256 + j0 + lk);
            As[lk + 0][lm] = av.x; As[lk + 1][lm] = av.y;
            As[lk + 2][lm] = av.z; As[lk + 3][lm] = av.w;
            Bs[lm][lk + 0] = bv.x; Bs[lm][lk + 1] = bv.y;
            Bs[lm][lk + 2] = bv.z; Bs[lm][lk + 3] = bv.w;
            __syncthreads();

#pragma unroll
            for (int kk = 0; kk < 32; ++kk) {
                float a0 = As[kk][ty * 2], a1 = As[kk][ty * 2 + 1];
                float b0 = Bs[kk][tx * 2], b1 = Bs[kk][tx * 2 + 1];
                acc[0][0] = fmaf(a0, b0, acc[0][0]);
                acc[0][1] = fmaf(a0, b1, acc[0][1]);
                acc[1][0] = fmaf(a1, b0, acc[1][0]);
                acc[1][1] = fmaf(a1, b1, acc[1][1]);
            }
            __syncthreads();
        }

#pragma unroll
        for (int i = 0; i < 2; ++i)
#pragma unroll
            for (int j = 0; j < 2; ++j)
                A2[(size_t)(i0 + ty * 2 + i) * 256 + j0 + tx * 2 + j] = acc[i][j];
    } else {
        // ---------------- offsets + counts + c1 = Wo2 @ bo1 ----------------
        if (tid < NGRP) {
            int g = tid;
            auto lb = [&](int val) {
                int lo = 0, hi = NATOMS;
                while (lo < hi) {
                    int mid = (lo + hi) >> 1;
                    if (seg[mid] < val) lo = mid + 1; else hi = mid;
                }
                return lo;
            };
            int a = lb(g);
            int b = lb(g + 1);
            off[g] = a;
            if (g == NGRP - 1) off[NGRP] = NATOMS;
            cntf[g] = (float)(b - a);
        }
        // c1: each wave computes 64 outputs; lanes cover the 256-dim dot.
        int lane = tid & 63;
        int ww = tid >> 6;
        float4 b4 = ((const float4*)bo1)[lane];
        for (int i = ww * 64; i < ww * 64 + 64; ++i) {
            float4 wv = ((const float4*)(Wo2 + (size_t)i * 256))[lane];
            float p = wv.x * b4.x + wv.y * b4.y + wv.z * b4.z + wv.w * b4.w;
#pragma unroll
            for (int m = 32; m >= 1; m >>= 1)
                p += __shfl_xor(p, m, 64);
            if (lane == 0) c1[i] = p;
        }
    }
}

// ---------------------------------------------------------------------------
// K2: block-diagonal attention fused with per-group row-sum.
// Ysum[g, h*32+d] = sum_j (sum_i silu(q_i.k_j)) * v_j[d]. Grid (128, 8).
// ---------------------------------------------------------------------------
__global__ __launch_bounds__(256) void attn_kernel(
    const float* __restrict__ qkv, const int* __restrict__ off,
    float* __restrict__ Ysum)
{
    int g = blockIdx.x, h = blockIdx.y;
    int base = off[g];
    int end  = off[g + 1];
    base = min(max(base, 0), NATOMS);   // poison-safe clamps
    end  = min(max(end, base), NATOMS);
    int n = end - base;

    __shared__ float4 qt4[64 * 8];
    __shared__ float4 vt4[32 * 8];
    __shared__ float  wred[8][32];
    __shared__ float  w[32];
    __shared__ float  red[8][32];

    int tid = threadIdx.x;
    int jj = tid & 31;
    int iq = tid >> 5;
    int d = tid & 31;
    int r = tid >> 5;

    const float* q = qkv;
    const float* k = qkv + (size_t)NATOMS * FDIM;
    const float* v = qkv + 2 * (size_t)NATOMS * FDIM;

    const float4* q4 = (const float4*)(q + (size_t)base * FDIM) + h * 8;
    const float4* k4 = (const float4*)(k + (size_t)base * FDIM) + h * 8;
    const float4* v4 = (const float4*)(v + (size_t)base * FDIM) + h * 8;

    float accY = 0.0f;

    for (int j0 = 0; j0 < n; j0 += 32) {
        int jt_n = min(32, n - j0);
        __syncthreads();
        for (int idx = tid; idx < jt_n * 8; idx += 256)
            vt4[idx] = v4[(size_t)(j0 + (idx >> 3)) * 64 + (idx & 7)];

        float4 kr[8];
        {
            int jrow = (jj < jt_n) ? (j0 + jj) : j0;
#pragma unroll
            for (int c = 0; c < 8; ++c) kr[c] = k4[(size_t)jrow * 64 + c];
        }

        float wpart = 0.0f;
        for (int i0 = 0; i0 < n; i0 += 64) {
            int it_n = min(64, n - i0);
            __syncthreads();
            for (int idx = tid; idx < it_n * 8; idx += 256)
                qt4[idx] = q4[(size_t)(i0 + (idx >> 3)) * 64 + (idx & 7)];
            __syncthreads();
            if (jj < jt_n) {
                for (int ii = iq; ii < it_n; ii += 8) {
                    const float4* qr = &qt4[ii * 8];
                    float s = 0.0f;
#pragma unroll
                    for (int c = 0; c < 8; ++c) {
                        float4 a = qr[c];
                        s = fmaf(a.x, kr[c].x, s);
                        s = fmaf(a.y, kr[c].y, s);
                        s = fmaf(a.z, kr[c].z, s);
                        s = fmaf(a.w, kr[c].w, s);
                    }
                    wpart += silu_f(s);
                }
            }
        }
        wred[iq][jj] = wpart;
        __syncthreads();
        if (tid < 32) {
            float s = 0.0f;
#pragma unroll
            for (int rr = 0; rr < 8; ++rr) s += wred[rr][tid];
            w[tid] = s;
        }
        __syncthreads();
        const float* vts = (const float*)vt4;
        for (int j = r; j < jt_n; j += 8)
            accY = fmaf(w[j], vts[j * 32 + d], accY);
    }

    red[r][d] = accY;
    __syncthreads();
    if (r == 0) {
        float s = 0.0f;
#pragma unroll
        for (int rr = 0; rr < 8; ++rr) s += red[rr][d];
        Ysum[(size_t)g * FDIM + h * DHEAD + d] = s;
    }
}

// ---------------------------------------------------------------------------
// K3: out[128,256] = silu(Ysum @ A2^T + cnt*c1 + bo2).  NT gemm, BM=16,
// BN=32, BK=32, 64 blocks, 256 threads (16x16, 1x2 micro-tile).
// ---------------------------------------------------------------------------
__global__ __launch_bounds__(256) void k3_tail(
    const float* __restrict__ Ysum, const float* __restrict__ A2,
    const float* __restrict__ c1, const float* __restrict__ bo2,
    const float* __restrict__ cntf, float* __restrict__ out)
{
    __shared__ float As[32][17];
    __shared__ float Bs[32][33];

    int tid = threadIdx.x;
    int bm = (blockIdx.x >> 3) * 16;   // 8 m-tiles
    int bn = (blockIdx.x & 7) * 32;    // 8 n-tiles
    int tx = tid & 15;
    int ty = tid >> 4;

    float acc0 = 0.0f, acc1 = 0.0f;

    for (int kt = 0; kt < 256; kt += 32) {
        if (tid < 128) {
            int row = tid >> 3, kq = (tid & 7) << 2;
            const float4 av = *(const float4*)(Ysum + (size_t)(bm + row) * 256 + kt + kq);
            As[kq + 0][row] = av.x; As[kq + 1][row] = av.y;
            As[kq + 2][row] = av.z; As[kq + 3][row] = av.w;
        }
        {
            int row = tid >> 3, kq = (tid & 7) << 2;
            const float4 bv = *(const float4*)(A2 + (size_t)(bn + row) * 256 + kt + kq);
            Bs[kq + 0][row] = bv.x; Bs[kq + 1][row] = bv.y;
            Bs[kq + 2][row] = bv.z; Bs[kq + 3][row] = bv.w;
        }
        __syncthreads();

#pragma unroll
        for (int kk = 0; kk < 32; ++kk) {
            float a = As[kk][ty];
            acc0 = fmaf(a, Bs[kk][tx * 2], acc0);
            acc1 = fmaf(a, Bs[kk][tx * 2 + 1], acc1);
        }
        __syncthreads();
    }

    int m = bm + ty;
    float cnt = cntf[m];
    int n0 = bn + tx * 2;
    float v0 = silu_f(acc0 + cnt * c1[n0] + bo2[n0]);
    float v1 = silu_f(acc1 + cnt * c1[n0 + 1] + bo2[n0 + 1]);
    out[(size_t)m * 256 + n0] = v0;
    out[(size_t)m * 256 + n0 + 1] = v1;
}

// ---------------------------------------------------------------------------
extern "C" void kernel_launch(void* const* d_in, const int* in_sizes, int n_in,
                              void* d_out, int out_size, void* d_ws, size_t ws_size,
                              hipStream_t stream) {
    const float* x    = (const float*)d_in[0];
    const int*   eidx = (const int*)  d_in[1];
    const float* Wq   = (const float*)d_in[2];
    const float* bq   = (const float*)d_in[3];
    const float* Wk   = (const float*)d_in[4];
    const float* bk   = (const float*)d_in[5];
    const float* Wv   = (const float*)d_in[6];
    const float* bv   = (const float*)d_in[7];
    const float* Wo1  = (const float*)d_in[8];
    const float* bo1  = (const float*)d_in[9];
    const float* Wo2  = (const float*)d_in[10];
    const float* bo2  = (const float*)d_in[11];
    float* out = (float*)d_out;

    const int* seg = eidx + NATOMS;

    const size_t NF = (size_t)NATOMS * FDIM;   // 1,048,576
    const size_t GF = (size_t)NGRP * FDIM;     // 32,768

    float* qkv  = (float*)d_ws;                // q|k|v contiguous, 3*NF
    float* Ysum = qkv + 3 * NF;                // GF
    float* A2   = Ysum + GF;                   // 256*256
    float* c1   = A2 + 256 * 256;              // 256
    float* cntf = c1 + 256;                    // 128
    int*   off  = (int*)(cntf + NGRP);         // 129 ints

    k1_qkv_a2<<<577, 256, 0, stream>>>(x, seg, Wq, Wk, Wv, bq, bk, bv,
                                       Wo1, bo1, Wo2, qkv, A2, c1, cntf, off);

    dim3 gattn(NGRP, NHEAD);
    attn_kernel<<<gattn, 256, 0, stream>>>(qkv, off, Ysum);

    k3_tail<<<64, 256, 0, stream>>>(Ysum, A2, c1, bo2, cntf, out);
}

// Round 6
// 131.696 us; speedup vs baseline: 2.0477x; 1.1634x over previous
//
#include <hip/hip_runtime.h>
#include <math.h>

#define NATOMS 4096
#define FDIM   256
#define NHEAD  8
#define DHEAD  32
#define NGRP   128

typedef __bf16 bf16x8 __attribute__((ext_vector_type(8)));
typedef float  floatx4 __attribute__((ext_vector_type(4)));

__device__ __forceinline__ float silu_f(float x) {
    return x / (1.0f + __expf(-x));
}

// load 8 consecutive fp32 and convert to a bf16x8 MFMA fragment (RNE)
__device__ __forceinline__ bf16x8 cvt8(const float* __restrict__ p) {
    float4 f0 = *(const float4*)p;
    float4 f1 = *(const float4*)(p + 4);
    bf16x8 r;
    r[0] = (__bf16)f0.x; r[1] = (__bf16)f0.y; r[2] = (__bf16)f0.z; r[3] = (__bf16)f0.w;
    r[4] = (__bf16)f1.x; r[5] = (__bf16)f1.y; r[6] = (__bf16)f1.z; r[7] = (__bf16)f1.w;
    return r;
}

// ---------------------------------------------------------------------------
// K1: 577 blocks.
//  bid <  512 : QKV projection tile via bf16 MFMA, fp32 inputs cvt'd inline.
//               D[4096,768] = x @ [Wq|Wk|Wv]^T + bias -> fp32 q|k|v.
//  512..575   : A2 = Wo2 @ Wo1 (fp32 NN, 32x32 tiles). Blocks with j0==0
//               also fold c1 = Wo2 @ bo1 out of their LDS-staged Wo2 tile.
//  bid == 576 : group offsets + counts via LDS-staged seg (no cold-HBM
//               dependent-load chains — that was the R5 51 us straggler).
// ---------------------------------------------------------------------------
__global__ __launch_bounds__(256) void k1_qkv_a2(
    const float* __restrict__ x, const int* __restrict__ seg,
    const float* __restrict__ Wq, const float* __restrict__ Wk, const float* __restrict__ Wv,
    const float* __restrict__ bq, const float* __restrict__ bk, const float* __restrict__ bv,
    const float* __restrict__ Wo1, const float* __restrict__ bo1,
    const float* __restrict__ Wo2,
    float* __restrict__ qkv, float* __restrict__ A2, float* __restrict__ c1,
    float* __restrict__ cntf, int* __restrict__ off)
{
    __shared__ float As[32][33];
    __shared__ float Bs[32][33];
    __shared__ int   segs[NATOMS];

    const int tid = threadIdx.x;
    const int bid = blockIdx.x;

    if (bid < 512) {
        // ---------------- QKV MFMA tile ----------------
        int lane = tid & 63;
        int ww = tid >> 6;
        int wrow = ww >> 1, wcol = ww & 1;
        int tm = bid & 63;
        int tn = bid >> 6;                 // 0..7
        int m_base = tm * 64 + wrow * 32;
        int n_base = tn * 96 + wcol * 48;

        int l15 = lane & 15;
        int quad = lane >> 4;
        int kq = quad * 8;

        floatx4 acc[2][3] = {};

        const float* arow0 = x + (size_t)(m_base + l15) * 256 + kq;
        const float* arow1 = arow0 + 16 * 256;
        const float* brow[3];
        const float* bias[3];
#pragma unroll
        for (int ni = 0; ni < 3; ++ni) {
            int col = n_base + ni * 16 + l15;
            int w = col >> 8, c = col & 255;
            const float* W = (w == 0) ? Wq : (w == 1) ? Wk : Wv;
            brow[ni] = W + (size_t)c * 256 + kq;
            bias[ni] = ((w == 0) ? bq : (w == 1) ? bk : bv) + c;
        }

#pragma unroll
        for (int ks = 0; ks < 8; ++ks) {
            int ko = ks * 32;
            bf16x8 a0 = cvt8(arow0 + ko);
            bf16x8 a1 = cvt8(arow1 + ko);
#pragma unroll
            for (int ni = 0; ni < 3; ++ni) {
                bf16x8 b = cvt8(brow[ni] + ko);
                acc[0][ni] = __builtin_amdgcn_mfma_f32_16x16x32_bf16(a0, b, acc[0][ni], 0, 0, 0);
                acc[1][ni] = __builtin_amdgcn_mfma_f32_16x16x32_bf16(a1, b, acc[1][ni], 0, 0, 0);
            }
        }

#pragma unroll
        for (int mi = 0; mi < 2; ++mi) {
#pragma unroll
            for (int ni = 0; ni < 3; ++ni) {
                int col = n_base + ni * 16 + l15;
                int w = col >> 8, c = col & 255;
                float bb = *bias[ni];
                float* outp = qkv + (size_t)w * ((size_t)NATOMS * FDIM) + c;
#pragma unroll
                for (int r = 0; r < 4; ++r) {
                    int row = m_base + mi * 16 + quad * 4 + r;
                    outp[(size_t)row * FDIM] = acc[mi][ni][r] + bb;
                }
            }
        }
    } else if (bid < 576) {
        // ------- A2 = Wo2 @ Wo1 (fp32 NN, 32x32 tile); j0==0 blocks: + c1 -------
        int t = bid - 512;
        int i0 = (t >> 3) * 32;
        int j0 = (t & 7) * 32;
        bool do_c1 = (t & 7) == 0;
        int tx = tid & 15;
        int ty = tid >> 4;
        int lm = tid >> 3;              // 0..31 (row in tile)
        int lk = (tid & 7) << 2;        // 0..28 (k offset)

        float acc[2][2] = {};
        float c1acc = 0.0f;

        for (int kt = 0; kt < 256; kt += 32) {
            const float4 av = *(const float4*)(Wo2 + (size_t)(i0 + lm) * 256 + kt + lk);
            const float4 bv = *(const float4*)(Wo1 + (size_t)(kt + lm) * 256 + j0 + lk);
            As[lk + 0][lm] = av.x; As[lk + 1][lm] = av.y;
            As[lk + 2][lm] = av.z; As[lk + 3][lm] = av.w;
            Bs[lm][lk + 0] = bv.x; Bs[lm][lk + 1] = bv.y;
            Bs[lm][lk + 2] = bv.z; Bs[lm][lk + 3] = bv.w;
            __syncthreads();

#pragma unroll
            for (int kk = 0; kk < 32; ++kk) {
                float a0 = As[kk][ty * 2], a1 = As[kk][ty * 2 + 1];
                float b0 = Bs[kk][tx * 2], b1 = Bs[kk][tx * 2 + 1];
                acc[0][0] = fmaf(a0, b0, acc[0][0]);
                acc[0][1] = fmaf(a0, b1, acc[0][1]);
                acc[1][0] = fmaf(a1, b0, acc[1][0]);
                acc[1][1] = fmaf(a1, b1, acc[1][1]);
            }
            if (do_c1) {
                // c1 partial from the already-staged Wo2 tile:
                // As[lk+c][lm] = Wo2[i0+lm, kt+lk+c]
                float4 bb = *(const float4*)(bo1 + kt + lk);
                c1acc = fmaf(As[lk + 0][lm], bb.x, c1acc);
                c1acc = fmaf(As[lk + 1][lm], bb.y, c1acc);
                c1acc = fmaf(As[lk + 2][lm], bb.z, c1acc);
                c1acc = fmaf(As[lk + 3][lm], bb.w, c1acc);
            }
            __syncthreads();
        }

#pragma unroll
        for (int i = 0; i < 2; ++i)
#pragma unroll
            for (int j = 0; j < 2; ++j)
                A2[(size_t)(i0 + ty * 2 + i) * 256 + j0 + tx * 2 + j] = acc[i][j];

        if (do_c1) {
            // reduce the 8 k-group partials (consecutive lanes share lm)
            c1acc += __shfl_xor(c1acc, 1, 8);
            c1acc += __shfl_xor(c1acc, 2, 8);
            c1acc += __shfl_xor(c1acc, 4, 8);
            if ((tid & 7) == 0) c1[i0 + lm] = c1acc;
        }
    } else {
        // ---------------- offsets + counts via LDS-staged seg ----------------
        for (int i = tid; i < NATOMS; i += 256) segs[i] = seg[i];
        __syncthreads();
        if (tid < NGRP) {
            int g = tid;
            auto lb = [&](int val) {
                int lo = 0, hi = NATOMS;
                while (lo < hi) {
                    int mid = (lo + hi) >> 1;
                    if (segs[mid] < val) lo = mid + 1; else hi = mid;
                }
                return lo;
            };
            int a = lb(g);
            int b = lb(g + 1);
            off[g] = a;
            if (g == NGRP - 1) off[NGRP] = NATOMS;
            cntf[g] = (float)(b - a);
        }
    }
}

// ---------------------------------------------------------------------------
// K2: block-diagonal attention fused with per-group row-sum.
// Ysum[g, h*32+d] = sum_j (sum_i silu(q_i.k_j)) * v_j[d]. Grid (128, 8).
// ---------------------------------------------------------------------------
__global__ __launch_bounds__(256) void attn_kernel(
    const float* __restrict__ qkv, const int* __restrict__ off,
    float* __restrict__ Ysum)
{
    int g = blockIdx.x, h = blockIdx.y;
    int base = off[g];
    int end  = off[g + 1];
    base = min(max(base, 0), NATOMS);   // poison-safe clamps
    end  = min(max(end, base), NATOMS);
    int n = end - base;

    __shared__ float4 qt4[64 * 8];
    __shared__ float4 vt4[32 * 8];
    __shared__ float  wred[8][32];
    __shared__ float  w[32];
    __shared__ float  red[8][32];

    int tid = threadIdx.x;
    int jj = tid & 31;
    int iq = tid >> 5;
    int d = tid & 31;
    int r = tid >> 5;

    const float* q = qkv;
    const float* k = qkv + (size_t)NATOMS * FDIM;
    const float* v = qkv + 2 * (size_t)NATOMS * FDIM;

    const float4* q4 = (const float4*)(q + (size_t)base * FDIM) + h * 8;
    const float4* k4 = (const float4*)(k + (size_t)base * FDIM) + h * 8;
    const float4* v4 = (const float4*)(v + (size_t)base * FDIM) + h * 8;

    float accY = 0.0f;

    for (int j0 = 0; j0 < n; j0 += 32) {
        int jt_n = min(32, n - j0);
        __syncthreads();
        for (int idx = tid; idx < jt_n * 8; idx += 256)
            vt4[idx] = v4[(size_t)(j0 + (idx >> 3)) * 64 + (idx & 7)];

        float4 kr[8];
        {
            int jrow = (jj < jt_n) ? (j0 + jj) : j0;
#pragma unroll
            for (int c = 0; c < 8; ++c) kr[c] = k4[(size_t)jrow * 64 + c];
        }

        float wpart = 0.0f;
        for (int i0 = 0; i0 < n; i0 += 64) {
            int it_n = min(64, n - i0);
            __syncthreads();
            for (int idx = tid; idx < it_n * 8; idx += 256)
                qt4[idx] = q4[(size_t)(i0 + (idx >> 3)) * 64 + (idx & 7)];
            __syncthreads();
            if (jj < jt_n) {
                for (int ii = iq; ii < it_n; ii += 8) {
                    const float4* qr = &qt4[ii * 8];
                    float s = 0.0f;
#pragma unroll
                    for (int c = 0; c < 8; ++c) {
                        float4 a = qr[c];
                        s = fmaf(a.x, kr[c].x, s);
                        s = fmaf(a.y, kr[c].y, s);
                        s = fmaf(a.z, kr[c].z, s);
                        s = fmaf(a.w, kr[c].w, s);
                    }
                    wpart += silu_f(s);
                }
            }
        }
        wred[iq][jj] = wpart;
        __syncthreads();
        if (tid < 32) {
            float s = 0.0f;
#pragma unroll
            for (int rr = 0; rr < 8; ++rr) s += wred[rr][tid];
            w[tid] = s;
        }
        __syncthreads();
        const float* vts = (const float*)vt4;
        for (int j = r; j < jt_n; j += 8)
            accY = fmaf(w[j], vts[j * 32 + d], accY);
    }

    red[r][d] = accY;
    __syncthreads();
    if (r == 0) {
        float s = 0.0f;
#pragma unroll
        for (int rr = 0; rr < 8; ++rr) s += red[rr][d];
        Ysum[(size_t)g * FDIM + h * DHEAD + d] = s;
    }
}

// ---------------------------------------------------------------------------
// K3: out[128,256] = silu(Ysum @ A2^T + cnt*c1 + bo2).  NT gemm, BM=16,
// BN=32, BK=32, 64 blocks, 256 threads (16x16, 1x2 micro-tile).
// ---------------------------------------------------------------------------
__global__ __launch_bounds__(256) void k3_tail(
    const float* __restrict__ Ysum, const float* __restrict__ A2,
    const float* __restrict__ c1, const float* __restrict__ bo2,
    const float* __restrict__ cntf, float* __restrict__ out)
{
    __shared__ float As[32][17];
    __shared__ float Bs[32][33];

    int tid = threadIdx.x;
    int bm = (blockIdx.x >> 3) * 16;   // 8 m-tiles
    int bn = (blockIdx.x & 7) * 32;    // 8 n-tiles
    int tx = tid & 15;
    int ty = tid >> 4;

    float acc0 = 0.0f, acc1 = 0.0f;

    for (int kt = 0; kt < 256; kt += 32) {
        if (tid < 128) {
            int row = tid >> 3, kq = (tid & 7) << 2;
            const float4 av = *(const float4*)(Ysum + (size_t)(bm + row) * 256 + kt + kq);
            As[kq + 0][row] = av.x; As[kq + 1][row] = av.y;
            As[kq + 2][row] = av.z; As[kq + 3][row] = av.w;
        }
        {
            int row = tid >> 3, kq = (tid & 7) << 2;
            const float4 bv = *(const float4*)(A2 + (size_t)(bn + row) * 256 + kt + kq);
            Bs[kq + 0][row] = bv.x; Bs[kq + 1][row] = bv.y;
            Bs[kq + 2][row] = bv.z; Bs[kq + 3][row] = bv.w;
        }
        __syncthreads();

#pragma unroll
        for (int kk = 0; kk < 32; ++kk) {
            float a = As[kk][ty];
            acc0 = fmaf(a, Bs[kk][tx * 2], acc0);
            acc1 = fmaf(a, Bs[kk][tx * 2 + 1], acc1);
        }
        __syncthreads();
    }

    int m = bm + ty;
    float cnt = cntf[m];
    int n0 = bn + tx * 2;
    float v0 = silu_f(acc0 + cnt * c1[n0] + bo2[n0]);
    float v1 = silu_f(acc1 + cnt * c1[n0 + 1] + bo2[n0 + 1]);
    out[(size_t)m * 256 + n0] = v0;
    out[(size_t)m * 256 + n0 + 1] = v1;
}

// ---------------------------------------------------------------------------
extern "C" void kernel_launch(void* const* d_in, const int* in_sizes, int n_in,
                              void* d_out, int out_size, void* d_ws, size_t ws_size,
                              hipStream_t stream) {
    const float* x    = (const float*)d_in[0];
    const int*   eidx = (const int*)  d_in[1];
    const float* Wq   = (const float*)d_in[2];
    const float* bq   = (const float*)d_in[3];
    const float* Wk   = (const float*)d_in[4];
    const float* bk   = (const float*)d_in[5];
    const float* Wv   = (const float*)d_in[6];
    const float* bv   = (const float*)d_in[7];
    const float* Wo1  = (const float*)d_in[8];
    const float* bo1  = (const float*)d_in[9];
    const float* Wo2  = (const float*)d_in[10];
    const float* bo2  = (const float*)d_in[11];
    float* out = (float*)d_out;

    const int* seg = eidx + NATOMS;

    const size_t NF = (size_t)NATOMS * FDIM;   // 1,048,576
    const size_t GF = (size_t)NGRP * FDIM;     // 32,768

    float* qkv  = (float*)d_ws;                // q|k|v contiguous, 3*NF
    float* Ysum = qkv + 3 * NF;                // GF
    float* A2   = Ysum + GF;                   // 256*256
    float* c1   = A2 + 256 * 256;              // 256
    float* cntf = c1 + 256;                    // 128
    int*   off  = (int*)(cntf + NGRP);         // 129 ints

    k1_qkv_a2<<<577, 256, 0, stream>>>(x, seg, Wq, Wk, Wv, bq, bk, bv,
                                       Wo1, bo1, Wo2, qkv, A2, c1, cntf, off);

    dim3 gattn(NGRP, NHEAD);
    attn_kernel<<<gattn, 256, 0, stream>>>(qkv, off, Ysum);

    k3_tail<<<64, 256, 0, stream>>>(Ysum, A2, c1, bo2, cntf, out);
}